// Round 2
// baseline (293.966 us; speedup 1.0000x reference)
//
#include <hip/hip_runtime.h>
#include <hip/hip_bf16.h>
#include <stdint.h>

// ---------------------------------------------------------------------------
// MetaMultiHeadSelfAttention: B=4, S=2048, D=1024, H=16, hd=64, causal.
// R9: both projection GEMMs ported from the m97 128x128 structure (~690 TF,
// MfmaUtil 29%) to the 256x256 8-phase template (T2 chunk-XOR LDS swizzle +
// T3/T4 counted-vmcnt phase pipeline + T5 setprio + T1 XCD swizzle).
// Stage ring per group T (4 phases, 1 half-tile each):
//   p0: A-half0[T+1]  p1: A-half1[T+1]  p2: B-half1[T+1]  p3: B-half0[T+2]
// vmcnt(2) once per group at p3 covers all of tile T+1's halves before
// group T+1 reads them; every overwrite targets a buffer region whose last
// reads retired >=1 barrier earlier (lgkmcnt(0) precedes each end barrier).
// attn4 and the rest unchanged from R8 (passed, absmax 0.015625).
// ---------------------------------------------------------------------------

typedef __bf16 bf16x8 __attribute__((ext_vector_type(8)));
typedef __bf16 bf16x4 __attribute__((ext_vector_type(4)));
typedef float  f32x4  __attribute__((ext_vector_type(4)));

static __device__ __forceinline__ f32x4 mfma16(bf16x8 a, bf16x8 b, f32x4 c) {
  return __builtin_amdgcn_mfma_f32_16x16x32_bf16(a, b, c, 0, 0, 0);
}

// async 16B/lane global->LDS; LDS dest = wave-uniform base + lane*16
static __device__ __forceinline__ void load16_lds(const void* g, void* l) {
  __builtin_amdgcn_global_load_lds(
      (const __attribute__((address_space(1))) unsigned int*)g,
      (__attribute__((address_space(3))) unsigned int*)l, 16, 0, 0);
}

// ---------------------------------------------------------------------------
// fp32 -> bf16, 8 elems/thread
// ---------------------------------------------------------------------------
__global__ __launch_bounds__(256) void cvt_f32_bf16(
    const float* __restrict__ in, __bf16* __restrict__ out, int n8) {
  int i = blockIdx.x * blockDim.x + threadIdx.x;
  if (i >= n8) return;
  const float4* in4 = (const float4*)in;
  float4 a = in4[2 * i], b = in4[2 * i + 1];
  __bf16 v[8];
  v[0] = (__bf16)a.x; v[1] = (__bf16)a.y; v[2] = (__bf16)a.z; v[3] = (__bf16)a.w;
  v[4] = (__bf16)b.x; v[5] = (__bf16)b.y; v[6] = (__bf16)b.z; v[7] = (__bf16)b.w;
  *(bf16x8*)(out + 8 * i) = *(bf16x8*)v;
}

// all 4 weight matrices in one launch: wq,wk,wv -> wqkv rows, wo -> wob.
// Wq is pre-scaled by 0.125 * log2(e) so attn can use exp2 with no multiply.
__global__ __launch_bounds__(256) void cvt_w(
    const float* __restrict__ w0, const float* __restrict__ w1,
    const float* __restrict__ w2, const float* __restrict__ w3,
    __bf16* __restrict__ wqkv, __bf16* __restrict__ wo) {
  int blk = blockIdx.x;                 // 2048 blocks, 512 per matrix
  int m = blk >> 9;
  const float* src = (m == 0) ? w0 : (m == 1) ? w1 : (m == 2) ? w2 : w3;
  __bf16* dst = (m < 3) ? (wqkv + (size_t)m * (1024 * 1024)) : wo;
  const float scl = (m == 0) ? 0.18033688011112042f : 1.0f;  // 0.125*log2(e)
  int i = (blk & 511) * 256 + threadIdx.x;
  const float4* in4 = (const float4*)src;
  float4 a = in4[2 * i], b = in4[2 * i + 1];
  __bf16 v[8];
  v[0] = (__bf16)(a.x * scl); v[1] = (__bf16)(a.y * scl);
  v[2] = (__bf16)(a.z * scl); v[3] = (__bf16)(a.w * scl);
  v[4] = (__bf16)(b.x * scl); v[5] = (__bf16)(b.y * scl);
  v[6] = (__bf16)(b.z * scl); v[7] = (__bf16)(b.w * scl);
  *(bf16x8*)(dst + 8 * i) = *(bf16x8*)v;
}

// ---------------------------------------------------------------------------
// 256x256 8-phase GEMM: C[M,N] = A[M,K] @ Bw[N,K]^T.
// 512 threads = 8 waves (2M x 4N), per-wave C = 128x64 (8 Mfrag x 4 Nfrag).
// BK=64; LDS = 2 dbuf x (A[256][64] + B[256][64]) bf16 = 128 KiB.
// LDS swizzle: 16B chunk c of row r stored at slot c ^ (r&7).
// ---------------------------------------------------------------------------
static __device__ __forceinline__ void stage_half(
    const __bf16* __restrict__ X, long row0, int K, long k0,
    __bf16* lds, int w, int lane) {
#pragma unroll
  for (int j = 0; j < 2; j++) {
    int rl = j * 64 + w * 8 + (lane >> 3);             // row within half
    int chunk = (lane & 7) ^ (rl & 7);                 // global chunk for slot lane&7
    load16_lds(X + (row0 + rl) * (long)K + k0 + chunk * 8,
               lds + (j * 64 + w * 8) * 64);           // wave-uniform base
  }
}

template <typename OutT>
__global__ __launch_bounds__(512, 2) void gemm_bt8(
    const __bf16* __restrict__ A, const __bf16* __restrict__ Bw,
    OutT* __restrict__ C, int M, int N, int K, int NX) {
  __shared__ __align__(16) __bf16 As[2][256 * 64];
  __shared__ __align__(16) __bf16 Bs[2][256 * 64];
  const int t = threadIdx.x;
  const int lane = t & 63, w = t >> 6;
  const int wm = w >> 2, wn = w & 3;
  const int l15 = lane & 15, quad = lane >> 4;

  // T1: bijective XCD swizzle (gridDim.x % 8 == 0 for both call sites)
  const int bid = blockIdx.x;
  const int cpx = gridDim.x >> 3;
  const int swz = (bid & 7) * cpx + (bid >> 3);
  const long m0 = (long)(swz / NX) * 256;
  const long n0 = (long)(swz % NX) * 256;

  // fragment read offsets (row R, chunk c -> elem R*64 + ((c^(R&7))<<3); R&7==l15&7)
  int aoff[8][2], boff[4][2];
#pragma unroll
  for (int mf = 0; mf < 8; mf++)
#pragma unroll
    for (int ks = 0; ks < 2; ks++)
      aoff[mf][ks] = (wm * 128 + mf * 16 + l15) * 64 + (((ks * 4 + quad) ^ (l15 & 7)) << 3);
#pragma unroll
  for (int nf = 0; nf < 4; nf++)
#pragma unroll
    for (int ks = 0; ks < 2; ks++)
      boff[nf][ks] = (wn * 64 + nf * 16 + l15) * 64 + (((ks * 4 + quad) ^ (l15 & 7)) << 3);

  const int NT = K >> 6;
  // prologue: tile0 (4 halves) + tile1 B-half0; vmcnt(2) leaves only the latter
  stage_half(A,  m0,       K, 0,  &As[0][0],        w, lane);
  stage_half(A,  m0 + 128, K, 0,  &As[0][128 * 64], w, lane);
  stage_half(Bw, n0,       K, 0,  &Bs[0][0],        w, lane);
  stage_half(Bw, n0 + 128, K, 0,  &Bs[0][128 * 64], w, lane);
  stage_half(Bw, n0,       K, 64, &Bs[1][0],        w, lane);
  asm volatile("s_waitcnt vmcnt(2)" ::: "memory");
  __builtin_amdgcn_s_barrier();

  f32x4 acc[8][4] = {};
  for (int T = 0; T < NT; T++) {
    __bf16* Acur = &As[T & 1][0];
    __bf16* Bcur = &Bs[T & 1][0];
    __bf16* Anx  = &As[(T + 1) & 1][0];
    __bf16* Bnx  = &Bs[(T + 1) & 1][0];
    const long kn = (long)(T + 1) * 64;
    const bool pf  = (T + 1 < NT);
    const bool pf2 = (T + 2 < NT);

    bf16x8 bfr[4][2];

    // ---------------- phase 0 : B-frags + mf 0,1 ----------------
    if (pf) stage_half(A, m0, K, kn, Anx, w, lane);
#pragma unroll
    for (int nf = 0; nf < 4; nf++)
#pragma unroll
      for (int ks = 0; ks < 2; ks++)
        bfr[nf][ks] = *(const bf16x8*)(Bcur + boff[nf][ks]);
    {
      bf16x8 a00 = *(const bf16x8*)(Acur + aoff[0][0]);
      bf16x8 a01 = *(const bf16x8*)(Acur + aoff[0][1]);
      bf16x8 a10 = *(const bf16x8*)(Acur + aoff[1][0]);
      bf16x8 a11 = *(const bf16x8*)(Acur + aoff[1][1]);
      __builtin_amdgcn_s_barrier();
      asm volatile("s_waitcnt lgkmcnt(0)" ::: "memory");
      __builtin_amdgcn_sched_barrier(0);
      __builtin_amdgcn_s_setprio(1);
#pragma unroll
      for (int nf = 0; nf < 4; nf++) {
        acc[0][nf] = mfma16(a00, bfr[nf][0], acc[0][nf]);
        acc[0][nf] = mfma16(a01, bfr[nf][1], acc[0][nf]);
        acc[1][nf] = mfma16(a10, bfr[nf][0], acc[1][nf]);
        acc[1][nf] = mfma16(a11, bfr[nf][1], acc[1][nf]);
      }
      __builtin_amdgcn_s_setprio(0);
      __builtin_amdgcn_s_barrier();
    }
    // ---------------- phase 1 : mf 2,3 ----------------
    if (pf) stage_half(A, m0 + 128, K, kn, Anx + 128 * 64, w, lane);
    {
      bf16x8 a00 = *(const bf16x8*)(Acur + aoff[2][0]);
      bf16x8 a01 = *(const bf16x8*)(Acur + aoff[2][1]);
      bf16x8 a10 = *(const bf16x8*)(Acur + aoff[3][0]);
      bf16x8 a11 = *(const bf16x8*)(Acur + aoff[3][1]);
      __builtin_amdgcn_s_barrier();
      asm volatile("s_waitcnt lgkmcnt(0)" ::: "memory");
      __builtin_amdgcn_sched_barrier(0);
      __builtin_amdgcn_s_setprio(1);
#pragma unroll
      for (int nf = 0; nf < 4; nf++) {
        acc[2][nf] = mfma16(a00, bfr[nf][0], acc[2][nf]);
        acc[2][nf] = mfma16(a01, bfr[nf][1], acc[2][nf]);
        acc[3][nf] = mfma16(a10, bfr[nf][0], acc[3][nf]);
        acc[3][nf] = mfma16(a11, bfr[nf][1], acc[3][nf]);
      }
      __builtin_amdgcn_s_setprio(0);
      __builtin_amdgcn_s_barrier();
    }
    // ---------------- phase 2 : mf 4,5 ----------------
    if (pf) stage_half(Bw, n0 + 128, K, kn, Bnx + 128 * 64, w, lane);
    {
      bf16x8 a00 = *(const bf16x8*)(Acur + aoff[4][0]);
      bf16x8 a01 = *(const bf16x8*)(Acur + aoff[4][1]);
      bf16x8 a10 = *(const bf16x8*)(Acur + aoff[5][0]);
      bf16x8 a11 = *(const bf16x8*)(Acur + aoff[5][1]);
      __builtin_amdgcn_s_barrier();
      asm volatile("s_waitcnt lgkmcnt(0)" ::: "memory");
      __builtin_amdgcn_sched_barrier(0);
      __builtin_amdgcn_s_setprio(1);
#pragma unroll
      for (int nf = 0; nf < 4; nf++) {
        acc[4][nf] = mfma16(a00, bfr[nf][0], acc[4][nf]);
        acc[4][nf] = mfma16(a01, bfr[nf][1], acc[4][nf]);
        acc[5][nf] = mfma16(a10, bfr[nf][0], acc[5][nf]);
        acc[5][nf] = mfma16(a11, bfr[nf][1], acc[5][nf]);
      }
      __builtin_amdgcn_s_setprio(0);
      __builtin_amdgcn_s_barrier();
    }
    // ---------------- phase 3 : mf 6,7 + vmcnt ----------------
    {
      bf16x8 a00 = *(const bf16x8*)(Acur + aoff[6][0]);
      bf16x8 a01 = *(const bf16x8*)(Acur + aoff[6][1]);
      bf16x8 a10 = *(const bf16x8*)(Acur + aoff[7][0]);
      bf16x8 a11 = *(const bf16x8*)(Acur + aoff[7][1]);
      if (pf2) {
        stage_half(Bw, n0, K, kn + 64, Bcur, w, lane);   // B-half0[T+2]; T's B dead
        asm volatile("s_waitcnt vmcnt(2)" ::: "memory"); // covers all of tile T+1
      } else {
        asm volatile("s_waitcnt vmcnt(0)" ::: "memory"); // tail drain
      }
      __builtin_amdgcn_s_barrier();
      asm volatile("s_waitcnt lgkmcnt(0)" ::: "memory");
      __builtin_amdgcn_sched_barrier(0);
      __builtin_amdgcn_s_setprio(1);
#pragma unroll
      for (int nf = 0; nf < 4; nf++) {
        acc[6][nf] = mfma16(a00, bfr[nf][0], acc[6][nf]);
        acc[6][nf] = mfma16(a01, bfr[nf][1], acc[6][nf]);
        acc[7][nf] = mfma16(a10, bfr[nf][0], acc[7][nf]);
        acc[7][nf] = mfma16(a11, bfr[nf][1], acc[7][nf]);
      }
      __builtin_amdgcn_s_setprio(0);
      __builtin_amdgcn_s_barrier();
    }
  }

  // epilogue
#pragma unroll
  for (int mf = 0; mf < 8; mf++)
#pragma unroll
    for (int nf = 0; nf < 4; nf++)
#pragma unroll
      for (int r = 0; r < 4; r++) {
        long row = m0 + wm * 128 + mf * 16 + quad * 4 + r;
        long col = n0 + wn * 64 + nf * 16 + l15;
        float v = acc[mf][nf][r];
        if constexpr (sizeof(OutT) == 2) C[row * (long)N + col] = (OutT)(__bf16)v;
        else                             C[row * (long)N + col] = v;
      }
}

// ---------------------------------------------------------------------------
// V transpose: QKV[b][s][2048 + h*64 + d] -> VT[(b*16+h)*64 + d][s]
// ---------------------------------------------------------------------------
__global__ __launch_bounds__(256) void vtrans(
    const __bf16* __restrict__ QKV, __bf16* __restrict__ VT) {
  constexpr int LDs = 136;
  __shared__ __align__(16) __bf16 Ts[64 * LDs];
  const int t = threadIdx.x;
  const int st0 = blockIdx.x * 128, h = blockIdx.y, b = blockIdx.z;
  const long vbase = (long)b * 2048 * 3072 + 2048 + h * 64;
#pragma unroll
  for (int i = 0; i < 4; i++) {
    int sl = i * 32 + (t >> 3), d0 = (t & 7) * 8;
    __bf16 tmp[8];
    *(uint4*)tmp = *(const uint4*)(QKV + vbase + (long)(st0 + sl) * 3072 + d0);
#pragma unroll
    for (int j = 0; j < 8; j++) Ts[(d0 + j) * LDs + sl] = tmp[j];
  }
  __syncthreads();
  const long obase = (long)(b * 16 + h) * 64 * 2048 + st0;
  const int d = t >> 2;
#pragma unroll
  for (int i = 0; i < 4; i++) {
    int sc = ((t & 3) + 4 * i) * 8;
    *(uint4*)(VT + obase + (long)d * 2048 + sc) = *(const uint4*)(Ts + d * LDs + sc);
  }
}

// ---------------------------------------------------------------------------
// Causal attention (R8 version, unchanged): double-buffered LDS K/VT,
// exp2 with pre-scaled Wq, ones-column MFMA for l, setprio, paired q-tiles.
// ---------------------------------------------------------------------------
__global__ __launch_bounds__(256) void attn4(
    const __bf16* __restrict__ QKV, const __bf16* __restrict__ VT,
    __bf16* __restrict__ O) {
  constexpr int SD = 3072;
  constexpr int LDP = 72;
  __shared__ __align__(16) __bf16 Ks[2][64 * 64];
  __shared__ __align__(16) __bf16 Vs[2][64 * 64];
  __shared__ __align__(16) __bf16 Pw[4 * 32 * LDP];
  const int t = threadIdx.x;
  const int lane = t & 63, w = t >> 6;
  const int l15 = lane & 15, quad = lane >> 4;
  const int jj = blockIdx.x, h = blockIdx.y, b = blockIdx.z;
  const long qbase = (long)b * 2048 * SD + h * 64;
  const long kbase = qbase + 1024;
  const long vtbase = (long)(b * 16 + h) * 64 * 2048;
  __bf16* Pme = Pw + w * 32 * LDP;

  const int sr = w * 16 + (lane >> 3);
  const int scg = (lane & 7) ^ (sr & 7);
  const int ldsOff = (w * 16) * 64;
  const __bf16* gK = QKV + kbase + (long)sr * SD + scg * 8;
  const __bf16* gV = VT + vtbase + (long)sr * 2048 + scg * 8;

  int kvoff[4][2];
#pragma unroll
  for (int nt = 0; nt < 4; nt++)
#pragma unroll
    for (int kk = 0; kk < 2; kk++)
      kvoff[nt][kk] = (nt * 16 + l15) * 64 + (((kk * 4 + quad) ^ (l15 & 7)) << 3);

  bf16x8 ones;
#pragma unroll
  for (int j = 0; j < 8; j++) ones[j] = (__bf16)1.0f;

#pragma unroll
  for (int half = 0; half < 2; half++) {
    const int qt = half ? (15 - jj) : jj;
    const int q0 = qt * 128;
    const int wrow0 = q0 + w * 32;

    bf16x8 qf[2][2];
#pragma unroll
    for (int mt = 0; mt < 2; mt++)
#pragma unroll
      for (int kk = 0; kk < 2; kk++)
        qf[mt][kk] = *(const bf16x8*)(QKV + qbase +
            (long)(wrow0 + mt * 16 + l15) * SD + kk * 32 + quad * 8);

    f32x4 o_acc[2][4] = {};
    f32x4 o_l[2] = {};

    const int nkt = 2 * qt + 2;

    __syncthreads();
    load16_lds(gK, Ks[0] + ldsOff);
    load16_lds(gK + 8 * SD, Ks[0] + ldsOff + 8 * 64);
    load16_lds(gV, Vs[0] + ldsOff);
    load16_lds(gV + 8 * 2048, Vs[0] + ldsOff + 8 * 64);

    int cur = 0;
    for (int kt = 0; kt < nkt; kt++) {
      __syncthreads();
      if (kt + 1 < nkt) {
        const __bf16* gKn = gK + (long)(kt + 1) * 64 * SD;
        const __bf16* gVn = gV + (kt + 1) * 64;
        __bf16* lk = Ks[cur ^ 1] + ldsOff;
        __bf16* lv = Vs[cur ^ 1] + ldsOff;
        load16_lds(gKn, lk);
        load16_lds(gKn + 8 * SD, lk + 8 * 64);
        load16_lds(gVn, lv);
        load16_lds(gVn + 8 * 2048, lv + 8 * 64);
      }

      const int k0 = kt * 64;
      if (k0 <= wrow0 + 31) {
        const __bf16* KsB = Ks[cur];
        const __bf16* VsB = Vs[cur];
        bf16x8 kf[4][2];
#pragma unroll
        for (int nt = 0; nt < 4; nt++)
#pragma unroll
          for (int kk = 0; kk < 2; kk++)
            kf[nt][kk] = *(const bf16x8*)(KsB + kvoff[nt][kk]);
        f32x4 st[4][2];
        __builtin_amdgcn_s_setprio(1);
#pragma unroll
        for (int nt = 0; nt < 4; nt++)
#pragma unroll
          for (int mt = 0; mt < 2; mt++) {
            f32x4 z = {0.f, 0.f, 0.f, 0.f};
            z = mfma16(kf[nt][0], qf[mt][0], z);
            st[nt][mt] = mfma16(kf[nt][1], qf[mt][1], z);
          }
        __builtin_amdgcn_s_setprio(0);

        if (k0 + 63 <= wrow0) {
#pragma unroll
          for (int mt = 0; mt < 2; mt++)
#pragma unroll
            for (int nt = 0; nt < 4; nt++) {
              bf16x4 pb;
#pragma unroll
              for (int r = 0; r < 4; r++)
                pb[r] = (__bf16)__builtin_amdgcn_exp2f(st[nt][mt][r]);
              *(bf16x4*)(Pme + (mt * 16 + l15) * LDP + nt * 16 + quad * 4) = pb;
            }
        } else {
#pragma unroll
          for (int mt = 0; mt < 2; mt++) {
            const int qrow = wrow0 + mt * 16 + l15;
#pragma unroll
            for (int nt = 0; nt < 4; nt++) {
              const int keyb = k0 + nt * 16 + quad * 4;
              bf16x4 pb;
#pragma unroll
              for (int r = 0; r < 4; r++) {
                float e = __builtin_amdgcn_exp2f(st[nt][mt][r]);
                if (keyb + r > qrow) e = 0.f;
                pb[r] = (__bf16)e;
              }
              *(bf16x4*)(Pme + (mt * 16 + l15) * LDP + nt * 16 + quad * 4) = pb;
            }
          }
        }

#pragma unroll
        for (int kk = 0; kk < 2; kk++) {
          bf16x8 vf[4];
#pragma unroll
          for (int dt = 0; dt < 4; dt++)
            vf[dt] = *(const bf16x8*)(VsB + kvoff[dt][kk]);
#pragma unroll
          for (int mt = 0; mt < 2; mt++) {
            bf16x8 pf = *(const bf16x8*)(Pme + (mt * 16 + l15) * LDP + kk * 32 + quad * 8);
            __builtin_amdgcn_s_setprio(1);
#pragma unroll
            for (int dt = 0; dt < 4; dt++)
              o_acc[mt][dt] = mfma16(pf, vf[dt], o_acc[mt][dt]);
            o_l[mt] = mfma16(pf, ones, o_l[mt]);
            __builtin_amdgcn_s_setprio(0);
          }
        }
      }
      cur ^= 1;
    }

#pragma unroll
    for (int mt = 0; mt < 2; mt++) {
#pragma unroll
      for (int r = 0; r < 4; r++) {
        float inv = 1.f / o_l[mt][r];
        int row = wrow0 + mt * 16 + quad * 4 + r;
        long ob = ((long)b * 2048 + row) * 1024 + h * 64;
#pragma unroll
        for (int dt = 0; dt < 4; dt++)
          O[ob + dt * 16 + l15] = (__bf16)(o_acc[mt][dt][r] * inv);
      }
    }
  }
}

// ---------------------------------------------------------------------------
extern "C" void kernel_launch(void* const* d_in, const int* in_sizes, int n_in,
                              void* d_out, int out_size, void* d_ws, size_t ws_size,
                              hipStream_t stream) {
  const float* x  = (const float*)d_in[0];
  const float* wq = (const float*)d_in[1];
  const float* wk = (const float*)d_in[2];
  const float* wv = (const float*)d_in[3];
  const float* wo = (const float*)d_in[4];
  float* out = (float*)d_out;

  char* ws = (char*)d_ws;
  __bf16* xb   = (__bf16*)(ws);               // 16 MB [8192,1024]; reused as Ab
  __bf16* wqkv = (__bf16*)(ws + (16l << 20)); //  6 MB [3072,1024]
  __bf16* wob  = (__bf16*)(ws + (22l << 20)); //  2 MB
  __bf16* QKV  = (__bf16*)(ws + (24l << 20)); // 48 MB [8192,3072]
  __bf16* VT   = (__bf16*)(ws + (72l << 20)); // 16 MB [4096,2048] -> 88 MB total
  __bf16* Ab   = xb;                          // x dead after QKV gemm

  cvt_f32_bf16<<<4096, 256, 0, stream>>>(x, xb, 8192 * 1024 / 8);
  cvt_w<<<2048, 256, 0, stream>>>(wq, wk, wv, wo, wqkv, wob);

  // fused QKV projection: [8192,3072] = xb @ wqkv^T  (32x12 = 384 blocks)
  gemm_bt8<__bf16><<<384, 512, 0, stream>>>(xb, wqkv, QKV, 8192, 3072, 1024, 12);

  // V -> VT [b,h,d,s]
  vtrans<<<dim3(16, 16, 4), 256, 0, stream>>>(QKV, VT);

  // causal attention (paired 128-row tiles, double-buffered K/VT) -> Ab
  attn4<<<dim3(8, 16, 4), 256, 0, stream>>>(QKV, VT, Ab);

  // output projection (fp32 out)  (32x4 = 128 blocks)
  gemm_bt8<float><<<128, 512, 0, stream>>>(Ab, wob, out, 8192, 1024, 1024, 4);
}

// Round 3
// 248.693 us; speedup vs baseline: 1.1820x; 1.1820x over previous
//
#include <hip/hip_runtime.h>
#include <hip/hip_bf16.h>
#include <stdint.h>

// ---------------------------------------------------------------------------
// MetaMultiHeadSelfAttention: B=4, S=2048, D=1024, H=16, hd=64, causal.
// R10: GEMM geometry fix after R9's regression (581 TF, MfmaUtil 22%).
// Diagnosis: (1) vmcnt cover was 1 phase (load issued p2, waited p3) ->
// full L2 latency exposed every K-tile; (2) 384 blocks / 256 CUs = 1.5
// rounds = 75% ceiling; (3) O-proj at 128 blocks = half machine idle.
// Fix: 256x128 tile, BK=64, TRIPLE-buffered LDS (144 KiB): tile T+2's
// buffers are dead since end of tile T-1, so all 6 stage-units of T+2
// issue during tile T (A at p0, B at p1) and the vmcnt(6) wait for tile
// T+1 covers loads issued a full tile (2-4 phases) earlier. QKV = 768
// blocks (3 exact rounds), O-proj = 256 blocks (1 exact round).
// attn4 / vtrans / cvt unchanged from R8 (passed, absmax 0.015625).
// ---------------------------------------------------------------------------

typedef __bf16 bf16x8 __attribute__((ext_vector_type(8)));
typedef __bf16 bf16x4 __attribute__((ext_vector_type(4)));
typedef float  f32x4  __attribute__((ext_vector_type(4)));

static __device__ __forceinline__ f32x4 mfma16(bf16x8 a, bf16x8 b, f32x4 c) {
  return __builtin_amdgcn_mfma_f32_16x16x32_bf16(a, b, c, 0, 0, 0);
}

// async 16B/lane global->LDS; LDS dest = wave-uniform base + lane*16
static __device__ __forceinline__ void load16_lds(const void* g, void* l) {
  __builtin_amdgcn_global_load_lds(
      (const __attribute__((address_space(1))) unsigned int*)g,
      (__attribute__((address_space(3))) unsigned int*)l, 16, 0, 0);
}

// ---------------------------------------------------------------------------
// fp32 -> bf16, 8 elems/thread
// ---------------------------------------------------------------------------
__global__ __launch_bounds__(256) void cvt_f32_bf16(
    const float* __restrict__ in, __bf16* __restrict__ out, int n8) {
  int i = blockIdx.x * blockDim.x + threadIdx.x;
  if (i >= n8) return;
  const float4* in4 = (const float4*)in;
  float4 a = in4[2 * i], b = in4[2 * i + 1];
  __bf16 v[8];
  v[0] = (__bf16)a.x; v[1] = (__bf16)a.y; v[2] = (__bf16)a.z; v[3] = (__bf16)a.w;
  v[4] = (__bf16)b.x; v[5] = (__bf16)b.y; v[6] = (__bf16)b.z; v[7] = (__bf16)b.w;
  *(bf16x8*)(out + 8 * i) = *(bf16x8*)v;
}

// all 4 weight matrices in one launch: wq,wk,wv -> wqkv rows, wo -> wob.
// Wq is pre-scaled by 0.125 * log2(e) so attn can use exp2 with no multiply.
__global__ __launch_bounds__(256) void cvt_w(
    const float* __restrict__ w0, const float* __restrict__ w1,
    const float* __restrict__ w2, const float* __restrict__ w3,
    __bf16* __restrict__ wqkv, __bf16* __restrict__ wo) {
  int blk = blockIdx.x;                 // 2048 blocks, 512 per matrix
  int m = blk >> 9;
  const float* src = (m == 0) ? w0 : (m == 1) ? w1 : (m == 2) ? w2 : w3;
  __bf16* dst = (m < 3) ? (wqkv + (size_t)m * (1024 * 1024)) : wo;
  const float scl = (m == 0) ? 0.18033688011112042f : 1.0f;  // 0.125*log2(e)
  int i = (blk & 511) * 256 + threadIdx.x;
  const float4* in4 = (const float4*)src;
  float4 a = in4[2 * i], b = in4[2 * i + 1];
  __bf16 v[8];
  v[0] = (__bf16)(a.x * scl); v[1] = (__bf16)(a.y * scl);
  v[2] = (__bf16)(a.z * scl); v[3] = (__bf16)(a.w * scl);
  v[4] = (__bf16)(b.x * scl); v[5] = (__bf16)(b.y * scl);
  v[6] = (__bf16)(b.z * scl); v[7] = (__bf16)(b.w * scl);
  *(bf16x8*)(dst + 8 * i) = *(bf16x8*)v;
}

// ---------------------------------------------------------------------------
// 256x128 triple-buffered 2-phase GEMM: C[M,N] = A[M,K] @ Bw[N,K]^T.
// 512 threads = 8 waves (4M x 2N), per-wave C = 64x64 (4 Mfrag x 4 Nfrag).
// BK=64; LDS = 3 x (A[256][64] + B[128][64]) bf16 = 144 KiB.
// LDS swizzle: 16B chunk c of row r stored at slot c ^ (r&7) (0 conflicts,
// verified R9). Stage unit = 64 rows x 64 cols = 1 global_load_lds / thread.
// ---------------------------------------------------------------------------
static __device__ __forceinline__ void stage_unit(
    const __bf16* __restrict__ X, long grow0, int K, long k0,
    __bf16* lds, int t) {
  const int lane = t & 63, w = t >> 6;
  const int rl = w * 8 + (lane >> 3);                   // row within unit
  const int chunk = (lane & 7) ^ ((lane >> 3) & 7);     // row&7 == (lane>>3)&7
  load16_lds(X + (grow0 + rl) * (long)K + k0 + chunk * 8,
             lds + (w * 8) * 64);                       // wave-uniform base
}

template <typename OutT>
__global__ __launch_bounds__(512, 2) void gemm_bt8(
    const __bf16* __restrict__ A, const __bf16* __restrict__ Bw,
    OutT* __restrict__ C, int M, int N, int K, int NX) {
  __shared__ __align__(16) __bf16 As[3][256 * 64];
  __shared__ __align__(16) __bf16 Bs[3][128 * 64];
  const int t = threadIdx.x;
  const int lane = t & 63, w = t >> 6;
  const int wm = w >> 1, wn = w & 1;        // 4M x 2N waves
  const int l15 = lane & 15, quad = lane >> 4;

  // T1: bijective XCD swizzle (gridDim.x % 8 == 0 for both call sites)
  const int bid = blockIdx.x;
  const int cpx = gridDim.x >> 3;
  const int swz = (bid & 7) * cpx + (bid >> 3);
  const long m0 = (long)(swz / NX) * 256;
  const long n0 = (long)(swz % NX) * 128;

  // fragment read offsets (row R, chunk c -> elem R*64 + ((c^(R&7))<<3))
  int aoff[4][2], boff[4][2];
#pragma unroll
  for (int mf = 0; mf < 4; mf++)
#pragma unroll
    for (int ks = 0; ks < 2; ks++)
      aoff[mf][ks] = (wm * 64 + mf * 16 + l15) * 64 + (((ks * 4 + quad) ^ (l15 & 7)) << 3);
#pragma unroll
  for (int nf = 0; nf < 4; nf++)
#pragma unroll
    for (int ks = 0; ks < 2; ks++)
      boff[nf][ks] = (wn * 64 + nf * 16 + l15) * 64 + (((ks * 4 + quad) ^ (l15 & 7)) << 3);

  const int NT = K >> 6;
  __bf16 *Ac = As[0], *An = As[1], *Asg = As[2];
  __bf16 *Bc = Bs[0], *Bn = Bs[1], *Bsg = Bs[2];

  // prologue: tiles 0 and 1 fully staged; vmcnt(6) leaves tile1 in flight
#pragma unroll
  for (int u = 0; u < 4; u++) stage_unit(A, m0 + u * 64, K, 0, Ac + u * 64 * 64, t);
#pragma unroll
  for (int u = 0; u < 2; u++) stage_unit(Bw, n0 + u * 64, K, 0, Bc + u * 64 * 64, t);
#pragma unroll
  for (int u = 0; u < 4; u++) stage_unit(A, m0 + u * 64, K, 64, An + u * 64 * 64, t);
#pragma unroll
  for (int u = 0; u < 2; u++) stage_unit(Bw, n0 + u * 64, K, 64, Bn + u * 64 * 64, t);
  asm volatile("s_waitcnt vmcnt(6)" ::: "memory");
  __builtin_amdgcn_s_barrier();

  f32x4 acc[4][4] = {};
  for (int T = 0; T < NT; T++) {
    const bool pf2 = (T + 2 < NT);
    const long kn2 = (long)(T + 2) * 64;

    // ---------------- phase 0 : B-frags + mf 0,1 ----------------
    bf16x8 bfr[4][2];
#pragma unroll
    for (int nf = 0; nf < 4; nf++)
#pragma unroll
      for (int ks = 0; ks < 2; ks++)
        bfr[nf][ks] = *(const bf16x8*)(Bc + boff[nf][ks]);
    {
      bf16x8 a00 = *(const bf16x8*)(Ac + aoff[0][0]);
      bf16x8 a01 = *(const bf16x8*)(Ac + aoff[0][1]);
      bf16x8 a10 = *(const bf16x8*)(Ac + aoff[1][0]);
      bf16x8 a11 = *(const bf16x8*)(Ac + aoff[1][1]);
      if (pf2) {  // stage A of tile T+2 (buffer dead since end of tile T-1)
#pragma unroll
        for (int u = 0; u < 4; u++)
          stage_unit(A, m0 + u * 64, K, kn2, Asg + u * 64 * 64, t);
      }
      __builtin_amdgcn_s_barrier();
      asm volatile("s_waitcnt lgkmcnt(0)" ::: "memory");
      __builtin_amdgcn_sched_barrier(0);
      __builtin_amdgcn_s_setprio(1);
#pragma unroll
      for (int nf = 0; nf < 4; nf++) {
        acc[0][nf] = mfma16(a00, bfr[nf][0], acc[0][nf]);
        acc[0][nf] = mfma16(a01, bfr[nf][1], acc[0][nf]);
        acc[1][nf] = mfma16(a10, bfr[nf][0], acc[1][nf]);
        acc[1][nf] = mfma16(a11, bfr[nf][1], acc[1][nf]);
      }
      __builtin_amdgcn_s_setprio(0);
      __builtin_amdgcn_s_barrier();
    }
    // ---------------- phase 1 : mf 2,3 + counted vmcnt ----------------
    {
      bf16x8 a00 = *(const bf16x8*)(Ac + aoff[2][0]);
      bf16x8 a01 = *(const bf16x8*)(Ac + aoff[2][1]);
      bf16x8 a10 = *(const bf16x8*)(Ac + aoff[3][0]);
      bf16x8 a11 = *(const bf16x8*)(Ac + aoff[3][1]);
      if (pf2) {  // stage B of tile T+2, then wait for tile T+1 only
#pragma unroll
        for (int u = 0; u < 2; u++)
          stage_unit(Bw, n0 + u * 64, K, kn2, Bsg + u * 64 * 64, t);
        asm volatile("s_waitcnt vmcnt(6)" ::: "memory");  // T+2's 6 units stay
      } else {
        asm volatile("s_waitcnt vmcnt(0)" ::: "memory");  // tail drain
      }
      __builtin_amdgcn_s_barrier();
      asm volatile("s_waitcnt lgkmcnt(0)" ::: "memory");
      __builtin_amdgcn_sched_barrier(0);
      __builtin_amdgcn_s_setprio(1);
#pragma unroll
      for (int nf = 0; nf < 4; nf++) {
        acc[2][nf] = mfma16(a00, bfr[nf][0], acc[2][nf]);
        acc[2][nf] = mfma16(a01, bfr[nf][1], acc[2][nf]);
        acc[3][nf] = mfma16(a10, bfr[nf][0], acc[3][nf]);
        acc[3][nf] = mfma16(a11, bfr[nf][1], acc[3][nf]);
      }
      __builtin_amdgcn_s_setprio(0);
      __builtin_amdgcn_s_barrier();
    }
    // rotate buffers: cur <- nxt <- stage <- cur
    __bf16* ta = Ac; Ac = An; An = Asg; Asg = ta;
    __bf16* tb = Bc; Bc = Bn; Bn = Bsg; Bsg = tb;
  }

  // epilogue
#pragma unroll
  for (int mf = 0; mf < 4; mf++)
#pragma unroll
    for (int nf = 0; nf < 4; nf++)
#pragma unroll
      for (int r = 0; r < 4; r++) {
        long row = m0 + wm * 64 + mf * 16 + quad * 4 + r;
        long col = n0 + wn * 64 + nf * 16 + l15;
        float v = acc[mf][nf][r];
        if constexpr (sizeof(OutT) == 2) C[row * (long)N + col] = (OutT)(__bf16)v;
        else                             C[row * (long)N + col] = v;
      }
}

// ---------------------------------------------------------------------------
// V transpose: QKV[b][s][2048 + h*64 + d] -> VT[(b*16+h)*64 + d][s]
// ---------------------------------------------------------------------------
__global__ __launch_bounds__(256) void vtrans(
    const __bf16* __restrict__ QKV, __bf16* __restrict__ VT) {
  constexpr int LDs = 136;
  __shared__ __align__(16) __bf16 Ts[64 * LDs];
  const int t = threadIdx.x;
  const int st0 = blockIdx.x * 128, h = blockIdx.y, b = blockIdx.z;
  const long vbase = (long)b * 2048 * 3072 + 2048 + h * 64;
#pragma unroll
  for (int i = 0; i < 4; i++) {
    int sl = i * 32 + (t >> 3), d0 = (t & 7) * 8;
    __bf16 tmp[8];
    *(uint4*)tmp = *(const uint4*)(QKV + vbase + (long)(st0 + sl) * 3072 + d0);
#pragma unroll
    for (int j = 0; j < 8; j++) Ts[(d0 + j) * LDs + sl] = tmp[j];
  }
  __syncthreads();
  const long obase = (long)(b * 16 + h) * 64 * 2048 + st0;
  const int d = t >> 2;
#pragma unroll
  for (int i = 0; i < 4; i++) {
    int sc = ((t & 3) + 4 * i) * 8;
    *(uint4*)(VT + obase + (long)d * 2048 + sc) = *(const uint4*)(Ts + d * LDs + sc);
  }
}

// ---------------------------------------------------------------------------
// Causal attention (R8 version, unchanged): double-buffered LDS K/VT,
// exp2 with pre-scaled Wq, ones-column MFMA for l, setprio, paired q-tiles.
// ---------------------------------------------------------------------------
__global__ __launch_bounds__(256) void attn4(
    const __bf16* __restrict__ QKV, const __bf16* __restrict__ VT,
    __bf16* __restrict__ O) {
  constexpr int SD = 3072;
  constexpr int LDP = 72;
  __shared__ __align__(16) __bf16 Ks[2][64 * 64];
  __shared__ __align__(16) __bf16 Vs[2][64 * 64];
  __shared__ __align__(16) __bf16 Pw[4 * 32 * LDP];
  const int t = threadIdx.x;
  const int lane = t & 63, w = t >> 6;
  const int l15 = lane & 15, quad = lane >> 4;
  const int jj = blockIdx.x, h = blockIdx.y, b = blockIdx.z;
  const long qbase = (long)b * 2048 * SD + h * 64;
  const long kbase = qbase + 1024;
  const long vtbase = (long)(b * 16 + h) * 64 * 2048;
  __bf16* Pme = Pw + w * 32 * LDP;

  const int sr = w * 16 + (lane >> 3);
  const int scg = (lane & 7) ^ (sr & 7);
  const int ldsOff = (w * 16) * 64;
  const __bf16* gK = QKV + kbase + (long)sr * SD + scg * 8;
  const __bf16* gV = VT + vtbase + (long)sr * 2048 + scg * 8;

  int kvoff[4][2];
#pragma unroll
  for (int nt = 0; nt < 4; nt++)
#pragma unroll
    for (int kk = 0; kk < 2; kk++)
      kvoff[nt][kk] = (nt * 16 + l15) * 64 + (((kk * 4 + quad) ^ (l15 & 7)) << 3);

  bf16x8 ones;
#pragma unroll
  for (int j = 0; j < 8; j++) ones[j] = (__bf16)1.0f;

#pragma unroll
  for (int half = 0; half < 2; half++) {
    const int qt = half ? (15 - jj) : jj;
    const int q0 = qt * 128;
    const int wrow0 = q0 + w * 32;

    bf16x8 qf[2][2];
#pragma unroll
    for (int mt = 0; mt < 2; mt++)
#pragma unroll
      for (int kk = 0; kk < 2; kk++)
        qf[mt][kk] = *(const bf16x8*)(QKV + qbase +
            (long)(wrow0 + mt * 16 + l15) * SD + kk * 32 + quad * 8);

    f32x4 o_acc[2][4] = {};
    f32x4 o_l[2] = {};

    const int nkt = 2 * qt + 2;

    __syncthreads();
    load16_lds(gK, Ks[0] + ldsOff);
    load16_lds(gK + 8 * SD, Ks[0] + ldsOff + 8 * 64);
    load16_lds(gV, Vs[0] + ldsOff);
    load16_lds(gV + 8 * 2048, Vs[0] + ldsOff + 8 * 64);

    int cur = 0;
    for (int kt = 0; kt < nkt; kt++) {
      __syncthreads();
      if (kt + 1 < nkt) {
        const __bf16* gKn = gK + (long)(kt + 1) * 64 * SD;
        const __bf16* gVn = gV + (kt + 1) * 64;
        __bf16* lk = Ks[cur ^ 1] + ldsOff;
        __bf16* lv = Vs[cur ^ 1] + ldsOff;
        load16_lds(gKn, lk);
        load16_lds(gKn + 8 * SD, lk + 8 * 64);
        load16_lds(gVn, lv);
        load16_lds(gVn + 8 * 2048, lv + 8 * 64);
      }

      const int k0 = kt * 64;
      if (k0 <= wrow0 + 31) {
        const __bf16* KsB = Ks[cur];
        const __bf16* VsB = Vs[cur];
        bf16x8 kf[4][2];
#pragma unroll
        for (int nt = 0; nt < 4; nt++)
#pragma unroll
          for (int kk = 0; kk < 2; kk++)
            kf[nt][kk] = *(const bf16x8*)(KsB + kvoff[nt][kk]);
        f32x4 st[4][2];
        __builtin_amdgcn_s_setprio(1);
#pragma unroll
        for (int nt = 0; nt < 4; nt++)
#pragma unroll
          for (int mt = 0; mt < 2; mt++) {
            f32x4 z = {0.f, 0.f, 0.f, 0.f};
            z = mfma16(kf[nt][0], qf[mt][0], z);
            st[nt][mt] = mfma16(kf[nt][1], qf[mt][1], z);
          }
        __builtin_amdgcn_s_setprio(0);

        if (k0 + 63 <= wrow0) {
#pragma unroll
          for (int mt = 0; mt < 2; mt++)
#pragma unroll
            for (int nt = 0; nt < 4; nt++) {
              bf16x4 pb;
#pragma unroll
              for (int r = 0; r < 4; r++)
                pb[r] = (__bf16)__builtin_amdgcn_exp2f(st[nt][mt][r]);
              *(bf16x4*)(Pme + (mt * 16 + l15) * LDP + nt * 16 + quad * 4) = pb;
            }
        } else {
#pragma unroll
          for (int mt = 0; mt < 2; mt++) {
            const int qrow = wrow0 + mt * 16 + l15;
#pragma unroll
            for (int nt = 0; nt < 4; nt++) {
              const int keyb = k0 + nt * 16 + quad * 4;
              bf16x4 pb;
#pragma unroll
              for (int r = 0; r < 4; r++) {
                float e = __builtin_amdgcn_exp2f(st[nt][mt][r]);
                if (keyb + r > qrow) e = 0.f;
                pb[r] = (__bf16)e;
              }
              *(bf16x4*)(Pme + (mt * 16 + l15) * LDP + nt * 16 + quad * 4) = pb;
            }
          }
        }

#pragma unroll
        for (int kk = 0; kk < 2; kk++) {
          bf16x8 vf[4];
#pragma unroll
          for (int dt = 0; dt < 4; dt++)
            vf[dt] = *(const bf16x8*)(VsB + kvoff[dt][kk]);
#pragma unroll
          for (int mt = 0; mt < 2; mt++) {
            bf16x8 pf = *(const bf16x8*)(Pme + (mt * 16 + l15) * LDP + kk * 32 + quad * 8);
            __builtin_amdgcn_s_setprio(1);
#pragma unroll
            for (int dt = 0; dt < 4; dt++)
              o_acc[mt][dt] = mfma16(pf, vf[dt], o_acc[mt][dt]);
            o_l[mt] = mfma16(pf, ones, o_l[mt]);
            __builtin_amdgcn_s_setprio(0);
          }
        }
      }
      cur ^= 1;
    }

#pragma unroll
    for (int mt = 0; mt < 2; mt++) {
#pragma unroll
      for (int r = 0; r < 4; r++) {
        float inv = 1.f / o_l[mt][r];
        int row = wrow0 + mt * 16 + quad * 4 + r;
        long ob = ((long)b * 2048 + row) * 1024 + h * 64;
#pragma unroll
        for (int dt = 0; dt < 4; dt++)
          O[ob + dt * 16 + l15] = (__bf16)(o_acc[mt][dt][r] * inv);
      }
    }
  }
}

// ---------------------------------------------------------------------------
extern "C" void kernel_launch(void* const* d_in, const int* in_sizes, int n_in,
                              void* d_out, int out_size, void* d_ws, size_t ws_size,
                              hipStream_t stream) {
  const float* x  = (const float*)d_in[0];
  const float* wq = (const float*)d_in[1];
  const float* wk = (const float*)d_in[2];
  const float* wv = (const float*)d_in[3];
  const float* wo = (const float*)d_in[4];
  float* out = (float*)d_out;

  char* ws = (char*)d_ws;
  __bf16* xb   = (__bf16*)(ws);               // 16 MB [8192,1024]; reused as Ab
  __bf16* wqkv = (__bf16*)(ws + (16l << 20)); //  6 MB [3072,1024]
  __bf16* wob  = (__bf16*)(ws + (22l << 20)); //  2 MB
  __bf16* QKV  = (__bf16*)(ws + (24l << 20)); // 48 MB [8192,3072]
  __bf16* VT   = (__bf16*)(ws + (72l << 20)); // 16 MB [4096,2048] -> 88 MB total
  __bf16* Ab   = xb;                          // x dead after QKV gemm

  cvt_f32_bf16<<<4096, 256, 0, stream>>>(x, xb, 8192 * 1024 / 8);
  cvt_w<<<2048, 256, 0, stream>>>(wq, wk, wv, wo, wqkv, wob);

  // fused QKV projection: [8192,3072] = xb @ wqkv^T  (32x24 = 768 blocks, 3 exact rounds)
  gemm_bt8<__bf16><<<768, 512, 0, stream>>>(xb, wqkv, QKV, 8192, 3072, 1024, 24);

  // V -> VT [b,h,d,s]
  vtrans<<<dim3(16, 16, 4), 256, 0, stream>>>(QKV, VT);

  // causal attention (paired 128-row tiles, double-buffered K/VT) -> Ab
  attn4<<<dim3(8, 16, 4), 256, 0, stream>>>(QKV, VT, Ab);

  // output projection (fp32 out)  (32x8 = 256 blocks, 1 exact round)
  gemm_bt8<float><<<256, 512, 0, stream>>>(Ab, wob, out, 8192, 1024, 1024, 8);
}

// Round 4
// 241.760 us; speedup vs baseline: 1.2159x; 1.0287x over previous
//
#include <hip/hip_runtime.h>
#include <hip/hip_bf16.h>
#include <stdint.h>

// ---------------------------------------------------------------------------
// MetaMultiHeadSelfAttention: B=4, S=2048, D=1024, H=16, hd=64, causal.
// R11: attn4 staging-stall fix (GEMMs/vtrans/cvt unchanged from R10):
//   1. XCD-locality grid swizzle: 1-D grid of 512; all 8 jj-blocks of one
//      (h,b) group share bid&7 -> same XCD L2 -> K/V fetched ~once per XCD
//      (was: 8 sharers on 8 different XCDs -> 146 MB FETCH, HBM-latency
//      stalls every tile).
//   2. Triple-buffered K/V staging with counted vmcnt(4) + raw s_barrier
//      (replaces __syncthreads whose implicit vmcnt(0) capped prefetch at
//      depth 1). Prefetch kt+2 at tile kt -> 2 tiles (~1300 cy) of cover.
//      Ledger: top of kt: in-flight = tiles kt+1,kt+2 (8 loads) -> vmcnt(4)
//      retires kt for the arriving wave; barrier publishes all waves' kt.
//      Prefetch kt+2 overwrites buf (kt-1)%3 whose readers passed this
//      barrier. Tail: vmcnt(0) on the last tile (wave-uniform branch).
// ---------------------------------------------------------------------------

typedef __bf16 bf16x8 __attribute__((ext_vector_type(8)));
typedef __bf16 bf16x4 __attribute__((ext_vector_type(4)));
typedef float  f32x4  __attribute__((ext_vector_type(4)));

static __device__ __forceinline__ f32x4 mfma16(bf16x8 a, bf16x8 b, f32x4 c) {
  return __builtin_amdgcn_mfma_f32_16x16x32_bf16(a, b, c, 0, 0, 0);
}

// async 16B/lane global->LDS; LDS dest = wave-uniform base + lane*16
static __device__ __forceinline__ void load16_lds(const void* g, void* l) {
  __builtin_amdgcn_global_load_lds(
      (const __attribute__((address_space(1))) unsigned int*)g,
      (__attribute__((address_space(3))) unsigned int*)l, 16, 0, 0);
}

// ---------------------------------------------------------------------------
// fp32 -> bf16, 8 elems/thread
// ---------------------------------------------------------------------------
__global__ __launch_bounds__(256) void cvt_f32_bf16(
    const float* __restrict__ in, __bf16* __restrict__ out, int n8) {
  int i = blockIdx.x * blockDim.x + threadIdx.x;
  if (i >= n8) return;
  const float4* in4 = (const float4*)in;
  float4 a = in4[2 * i], b = in4[2 * i + 1];
  __bf16 v[8];
  v[0] = (__bf16)a.x; v[1] = (__bf16)a.y; v[2] = (__bf16)a.z; v[3] = (__bf16)a.w;
  v[4] = (__bf16)b.x; v[5] = (__bf16)b.y; v[6] = (__bf16)b.z; v[7] = (__bf16)b.w;
  *(bf16x8*)(out + 8 * i) = *(bf16x8*)v;
}

// all 4 weight matrices in one launch: wq,wk,wv -> wqkv rows, wo -> wob.
// Wq is pre-scaled by 0.125 * log2(e) so attn can use exp2 with no multiply.
__global__ __launch_bounds__(256) void cvt_w(
    const float* __restrict__ w0, const float* __restrict__ w1,
    const float* __restrict__ w2, const float* __restrict__ w3,
    __bf16* __restrict__ wqkv, __bf16* __restrict__ wo) {
  int blk = blockIdx.x;                 // 2048 blocks, 512 per matrix
  int m = blk >> 9;
  const float* src = (m == 0) ? w0 : (m == 1) ? w1 : (m == 2) ? w2 : w3;
  __bf16* dst = (m < 3) ? (wqkv + (size_t)m * (1024 * 1024)) : wo;
  const float scl = (m == 0) ? 0.18033688011112042f : 1.0f;  // 0.125*log2(e)
  int i = (blk & 511) * 256 + threadIdx.x;
  const float4* in4 = (const float4*)src;
  float4 a = in4[2 * i], b = in4[2 * i + 1];
  __bf16 v[8];
  v[0] = (__bf16)(a.x * scl); v[1] = (__bf16)(a.y * scl);
  v[2] = (__bf16)(a.z * scl); v[3] = (__bf16)(a.w * scl);
  v[4] = (__bf16)(b.x * scl); v[5] = (__bf16)(b.y * scl);
  v[6] = (__bf16)(b.z * scl); v[7] = (__bf16)(b.w * scl);
  *(bf16x8*)(dst + 8 * i) = *(bf16x8*)v;
}

// ---------------------------------------------------------------------------
// 256x128 triple-buffered 2-phase GEMM: C[M,N] = A[M,K] @ Bw[N,K]^T.
// 512 threads = 8 waves (4M x 2N), per-wave C = 64x64 (4 Mfrag x 4 Nfrag).
// BK=64; LDS = 3 x (A[256][64] + B[128][64]) bf16 = 144 KiB.
// ---------------------------------------------------------------------------
static __device__ __forceinline__ void stage_unit(
    const __bf16* __restrict__ X, long grow0, int K, long k0,
    __bf16* lds, int t) {
  const int lane = t & 63, w = t >> 6;
  const int rl = w * 8 + (lane >> 3);                   // row within unit
  const int chunk = (lane & 7) ^ ((lane >> 3) & 7);     // row&7 == (lane>>3)&7
  load16_lds(X + (grow0 + rl) * (long)K + k0 + chunk * 8,
             lds + (w * 8) * 64);                       // wave-uniform base
}

template <typename OutT>
__global__ __launch_bounds__(512, 2) void gemm_bt8(
    const __bf16* __restrict__ A, const __bf16* __restrict__ Bw,
    OutT* __restrict__ C, int M, int N, int K, int NX) {
  __shared__ __align__(16) __bf16 As[3][256 * 64];
  __shared__ __align__(16) __bf16 Bs[3][128 * 64];
  const int t = threadIdx.x;
  const int lane = t & 63, w = t >> 6;
  const int wm = w >> 1, wn = w & 1;        // 4M x 2N waves
  const int l15 = lane & 15, quad = lane >> 4;

  // T1: bijective XCD swizzle (gridDim.x % 8 == 0 for both call sites)
  const int bid = blockIdx.x;
  const int cpx = gridDim.x >> 3;
  const int swz = (bid & 7) * cpx + (bid >> 3);
  const long m0 = (long)(swz / NX) * 256;
  const long n0 = (long)(swz % NX) * 128;

  int aoff[4][2], boff[4][2];
#pragma unroll
  for (int mf = 0; mf < 4; mf++)
#pragma unroll
    for (int ks = 0; ks < 2; ks++)
      aoff[mf][ks] = (wm * 64 + mf * 16 + l15) * 64 + (((ks * 4 + quad) ^ (l15 & 7)) << 3);
#pragma unroll
  for (int nf = 0; nf < 4; nf++)
#pragma unroll
    for (int ks = 0; ks < 2; ks++)
      boff[nf][ks] = (wn * 64 + nf * 16 + l15) * 64 + (((ks * 4 + quad) ^ (l15 & 7)) << 3);

  const int NT = K >> 6;
  __bf16 *Ac = As[0], *An = As[1], *Asg = As[2];
  __bf16 *Bc = Bs[0], *Bn = Bs[1], *Bsg = Bs[2];

  // prologue: tiles 0 and 1 fully staged; vmcnt(6) leaves tile1 in flight
#pragma unroll
  for (int u = 0; u < 4; u++) stage_unit(A, m0 + u * 64, K, 0, Ac + u * 64 * 64, t);
#pragma unroll
  for (int u = 0; u < 2; u++) stage_unit(Bw, n0 + u * 64, K, 0, Bc + u * 64 * 64, t);
#pragma unroll
  for (int u = 0; u < 4; u++) stage_unit(A, m0 + u * 64, K, 64, An + u * 64 * 64, t);
#pragma unroll
  for (int u = 0; u < 2; u++) stage_unit(Bw, n0 + u * 64, K, 64, Bn + u * 64 * 64, t);
  asm volatile("s_waitcnt vmcnt(6)" ::: "memory");
  __builtin_amdgcn_s_barrier();

  f32x4 acc[4][4] = {};
  for (int T = 0; T < NT; T++) {
    const bool pf2 = (T + 2 < NT);
    const long kn2 = (long)(T + 2) * 64;

    // ---------------- phase 0 : B-frags + mf 0,1 ----------------
    bf16x8 bfr[4][2];
#pragma unroll
    for (int nf = 0; nf < 4; nf++)
#pragma unroll
      for (int ks = 0; ks < 2; ks++)
        bfr[nf][ks] = *(const bf16x8*)(Bc + boff[nf][ks]);
    {
      bf16x8 a00 = *(const bf16x8*)(Ac + aoff[0][0]);
      bf16x8 a01 = *(const bf16x8*)(Ac + aoff[0][1]);
      bf16x8 a10 = *(const bf16x8*)(Ac + aoff[1][0]);
      bf16x8 a11 = *(const bf16x8*)(Ac + aoff[1][1]);
      if (pf2) {
#pragma unroll
        for (int u = 0; u < 4; u++)
          stage_unit(A, m0 + u * 64, K, kn2, Asg + u * 64 * 64, t);
      }
      __builtin_amdgcn_s_barrier();
      asm volatile("s_waitcnt lgkmcnt(0)" ::: "memory");
      __builtin_amdgcn_sched_barrier(0);
      __builtin_amdgcn_s_setprio(1);
#pragma unroll
      for (int nf = 0; nf < 4; nf++) {
        acc[0][nf] = mfma16(a00, bfr[nf][0], acc[0][nf]);
        acc[0][nf] = mfma16(a01, bfr[nf][1], acc[0][nf]);
        acc[1][nf] = mfma16(a10, bfr[nf][0], acc[1][nf]);
        acc[1][nf] = mfma16(a11, bfr[nf][1], acc[1][nf]);
      }
      __builtin_amdgcn_s_setprio(0);
      __builtin_amdgcn_s_barrier();
    }
    // ---------------- phase 1 : mf 2,3 + counted vmcnt ----------------
    {
      bf16x8 a00 = *(const bf16x8*)(Ac + aoff[2][0]);
      bf16x8 a01 = *(const bf16x8*)(Ac + aoff[2][1]);
      bf16x8 a10 = *(const bf16x8*)(Ac + aoff[3][0]);
      bf16x8 a11 = *(const bf16x8*)(Ac + aoff[3][1]);
      if (pf2) {
#pragma unroll
        for (int u = 0; u < 2; u++)
          stage_unit(Bw, n0 + u * 64, K, kn2, Bsg + u * 64 * 64, t);
        asm volatile("s_waitcnt vmcnt(6)" ::: "memory");
      } else {
        asm volatile("s_waitcnt vmcnt(0)" ::: "memory");
      }
      __builtin_amdgcn_s_barrier();
      asm volatile("s_waitcnt lgkmcnt(0)" ::: "memory");
      __builtin_amdgcn_sched_barrier(0);
      __builtin_amdgcn_s_setprio(1);
#pragma unroll
      for (int nf = 0; nf < 4; nf++) {
        acc[2][nf] = mfma16(a00, bfr[nf][0], acc[2][nf]);
        acc[2][nf] = mfma16(a01, bfr[nf][1], acc[2][nf]);
        acc[3][nf] = mfma16(a10, bfr[nf][0], acc[3][nf]);
        acc[3][nf] = mfma16(a11, bfr[nf][1], acc[3][nf]);
      }
      __builtin_amdgcn_s_setprio(0);
      __builtin_amdgcn_s_barrier();
    }
    __bf16* ta = Ac; Ac = An; An = Asg; Asg = ta;
    __bf16* tb = Bc; Bc = Bn; Bn = Bsg; Bsg = tb;
  }

  // epilogue
#pragma unroll
  for (int mf = 0; mf < 4; mf++)
#pragma unroll
    for (int nf = 0; nf < 4; nf++)
#pragma unroll
      for (int r = 0; r < 4; r++) {
        long row = m0 + wm * 64 + mf * 16 + quad * 4 + r;
        long col = n0 + wn * 64 + nf * 16 + l15;
        float v = acc[mf][nf][r];
        if constexpr (sizeof(OutT) == 2) C[row * (long)N + col] = (OutT)(__bf16)v;
        else                             C[row * (long)N + col] = v;
      }
}

// ---------------------------------------------------------------------------
// V transpose: QKV[b][s][2048 + h*64 + d] -> VT[(b*16+h)*64 + d][s]
// ---------------------------------------------------------------------------
__global__ __launch_bounds__(256) void vtrans(
    const __bf16* __restrict__ QKV, __bf16* __restrict__ VT) {
  constexpr int LDs = 136;
  __shared__ __align__(16) __bf16 Ts[64 * LDs];
  const int t = threadIdx.x;
  const int st0 = blockIdx.x * 128, h = blockIdx.y, b = blockIdx.z;
  const long vbase = (long)b * 2048 * 3072 + 2048 + h * 64;
#pragma unroll
  for (int i = 0; i < 4; i++) {
    int sl = i * 32 + (t >> 3), d0 = (t & 7) * 8;
    __bf16 tmp[8];
    *(uint4*)tmp = *(const uint4*)(QKV + vbase + (long)(st0 + sl) * 3072 + d0);
#pragma unroll
    for (int j = 0; j < 8; j++) Ts[(d0 + j) * LDs + sl] = tmp[j];
  }
  __syncthreads();
  const long obase = (long)(b * 16 + h) * 64 * 2048 + st0;
  const int d = t >> 2;
#pragma unroll
  for (int i = 0; i < 4; i++) {
    int sc = ((t & 3) + 4 * i) * 8;
    *(uint4*)(VT + obase + (long)d * 2048 + sc) = *(const uint4*)(Ts + d * LDs + sc);
  }
}

// ---------------------------------------------------------------------------
// Causal attention, R11: XCD-locality swizzle + triple-buffered K/VT with
// counted vmcnt(4) + raw s_barrier (2-tile prefetch cover). Compute path
// (S^T MFMA, exp2, ones-column l, packed P via LDS) unchanged from R8.
// ---------------------------------------------------------------------------
__global__ __launch_bounds__(256) void attn4(
    const __bf16* __restrict__ QKV, const __bf16* __restrict__ VT,
    __bf16* __restrict__ O) {
  constexpr int SD = 3072;
  constexpr int LDP = 72;
  __shared__ __align__(16) __bf16 Ks[3][64 * 64];
  __shared__ __align__(16) __bf16 Vs[3][64 * 64];
  __shared__ __align__(16) __bf16 Pw[4 * 32 * LDP];
  const int t = threadIdx.x;
  const int lane = t & 63, w = t >> 6;
  const int l15 = lane & 15, quad = lane >> 4;

  // XCD-locality decode: all 8 jj of one (h,b) group share bid&7 -> same XCD
  const int bid = blockIdx.x;
  const int g = (bid & 7) * 8 + (bid >> 6);   // (h,b) group, 0..63
  const int jj = (bid >> 3) & 7;
  const int h = g & 15, b = g >> 4;

  const long qbase = (long)b * 2048 * SD + h * 64;
  const long kbase = qbase + 1024;
  const long vtbase = (long)(b * 16 + h) * 64 * 2048;
  __bf16* Pme = Pw + w * 32 * LDP;

  const int sr = w * 16 + (lane >> 3);
  const int scg = (lane & 7) ^ (sr & 7);
  const int ldsOff = (w * 16) * 64;
  const __bf16* gK = QKV + kbase + (long)sr * SD + scg * 8;
  const __bf16* gV = VT + vtbase + (long)sr * 2048 + scg * 8;

  int kvoff[4][2];
#pragma unroll
  for (int nt = 0; nt < 4; nt++)
#pragma unroll
    for (int kk = 0; kk < 2; kk++)
      kvoff[nt][kk] = (nt * 16 + l15) * 64 + (((kk * 4 + quad) ^ (l15 & 7)) << 3);

  bf16x8 ones;
#pragma unroll
  for (int j = 0; j < 8; j++) ones[j] = (__bf16)1.0f;

#pragma unroll
  for (int half = 0; half < 2; half++) {
    const int qt = half ? (15 - jj) : jj;
    const int q0 = qt * 128;
    const int wrow0 = q0 + w * 32;

    bf16x8 qf[2][2];
#pragma unroll
    for (int mt = 0; mt < 2; mt++)
#pragma unroll
      for (int kk = 0; kk < 2; kk++)
        qf[mt][kk] = *(const bf16x8*)(QKV + qbase +
            (long)(wrow0 + mt * 16 + l15) * SD + kk * 32 + quad * 8);

    f32x4 o_acc[2][4] = {};
    f32x4 o_l[2] = {};

    const int nkt = 2 * qt + 2;   // >= 2 always

    // protect buffers from previous half's readers, then stage tiles 0,1
    __syncthreads();
    load16_lds(gK, Ks[0] + ldsOff);
    load16_lds(gK + 8 * SD, Ks[0] + ldsOff + 8 * 64);
    load16_lds(gV, Vs[0] + ldsOff);
    load16_lds(gV + 8 * 2048, Vs[0] + ldsOff + 8 * 64);
    {
      const __bf16* gK1 = gK + (long)64 * SD;
      const __bf16* gV1 = gV + 64;
      load16_lds(gK1, Ks[1] + ldsOff);
      load16_lds(gK1 + 8 * SD, Ks[1] + ldsOff + 8 * 64);
      load16_lds(gV1, Vs[1] + ldsOff);
      load16_lds(gV1 + 8 * 2048, Vs[1] + ldsOff + 8 * 64);
    }

    int cur = 0;
    for (int kt = 0; kt < nkt; kt++) {
      // retire tile kt (own wave), publish via barrier (wave-uniform branch)
      if (kt + 1 < nkt) asm volatile("s_waitcnt vmcnt(4)" ::: "memory");
      else              asm volatile("s_waitcnt vmcnt(0)" ::: "memory");
      __builtin_amdgcn_s_barrier();
      __builtin_amdgcn_sched_barrier(0);

      if (kt + 2 < nkt) {   // prefetch kt+2 into buf (kt+2)%3 (= (kt-1)%3, dead)
        int stg = cur + 2; if (stg >= 3) stg -= 3;
        const __bf16* gKn = gK + (long)(kt + 2) * 64 * SD;
        const __bf16* gVn = gV + (kt + 2) * 64;
        load16_lds(gKn, Ks[stg] + ldsOff);
        load16_lds(gKn + 8 * SD, Ks[stg] + ldsOff + 8 * 64);
        load16_lds(gVn, Vs[stg] + ldsOff);
        load16_lds(gVn + 8 * 2048, Vs[stg] + ldsOff + 8 * 64);
      }

      const int k0 = kt * 64;
      if (k0 <= wrow0 + 31) {
        const __bf16* KsB = Ks[cur];
        const __bf16* VsB = Vs[cur];
        bf16x8 kf[4][2];
#pragma unroll
        for (int nt = 0; nt < 4; nt++)
#pragma unroll
          for (int kk = 0; kk < 2; kk++)
            kf[nt][kk] = *(const bf16x8*)(KsB + kvoff[nt][kk]);
        f32x4 st[4][2];
        __builtin_amdgcn_s_setprio(1);
#pragma unroll
        for (int nt = 0; nt < 4; nt++)
#pragma unroll
          for (int mt = 0; mt < 2; mt++) {
            f32x4 z = {0.f, 0.f, 0.f, 0.f};
            z = mfma16(kf[nt][0], qf[mt][0], z);
            st[nt][mt] = mfma16(kf[nt][1], qf[mt][1], z);
          }
        __builtin_amdgcn_s_setprio(0);

        if (k0 + 63 <= wrow0) {        // fully unmasked tile
#pragma unroll
          for (int mt = 0; mt < 2; mt++)
#pragma unroll
            for (int nt = 0; nt < 4; nt++) {
              bf16x4 pb;
#pragma unroll
              for (int r = 0; r < 4; r++)
                pb[r] = (__bf16)__builtin_amdgcn_exp2f(st[nt][mt][r]);
              *(bf16x4*)(Pme + (mt * 16 + l15) * LDP + nt * 16 + quad * 4) = pb;
            }
        } else {                       // diagonal tile: causal mask
#pragma unroll
          for (int mt = 0; mt < 2; mt++) {
            const int qrow = wrow0 + mt * 16 + l15;
#pragma unroll
            for (int nt = 0; nt < 4; nt++) {
              const int keyb = k0 + nt * 16 + quad * 4;
              bf16x4 pb;
#pragma unroll
              for (int r = 0; r < 4; r++) {
                float e = __builtin_amdgcn_exp2f(st[nt][mt][r]);
                if (keyb + r > qrow) e = 0.f;
                pb[r] = (__bf16)e;
              }
              *(bf16x4*)(Pme + (mt * 16 + l15) * LDP + nt * 16 + quad * 4) = pb;
            }
          }
        }

#pragma unroll
        for (int kk = 0; kk < 2; kk++) {
          bf16x8 vf[4];
#pragma unroll
          for (int dt = 0; dt < 4; dt++)
            vf[dt] = *(const bf16x8*)(VsB + kvoff[dt][kk]);
#pragma unroll
          for (int mt = 0; mt < 2; mt++) {
            bf16x8 pf = *(const bf16x8*)(Pme + (mt * 16 + l15) * LDP + kk * 32 + quad * 8);
            __builtin_amdgcn_s_setprio(1);
#pragma unroll
            for (int dt = 0; dt < 4; dt++)
              o_acc[mt][dt] = mfma16(pf, vf[dt], o_acc[mt][dt]);
            o_l[mt] = mfma16(pf, ones, o_l[mt]);
            __builtin_amdgcn_s_setprio(0);
          }
        }
      }
      cur = (cur == 2) ? 0 : cur + 1;
    }

    // epilogue: o_l holds per-row l in the exact o_acc row layout
#pragma unroll
    for (int mt = 0; mt < 2; mt++) {
#pragma unroll
      for (int r = 0; r < 4; r++) {
        float inv = 1.f / o_l[mt][r];
        int row = wrow0 + mt * 16 + quad * 4 + r;
        long ob = ((long)b * 2048 + row) * 1024 + h * 64;
#pragma unroll
        for (int dt = 0; dt < 4; dt++)
          O[ob + dt * 16 + l15] = (__bf16)(o_acc[mt][dt][r] * inv);
      }
    }
  }
}

// ---------------------------------------------------------------------------
extern "C" void kernel_launch(void* const* d_in, const int* in_sizes, int n_in,
                              void* d_out, int out_size, void* d_ws, size_t ws_size,
                              hipStream_t stream) {
  const float* x  = (const float*)d_in[0];
  const float* wq = (const float*)d_in[1];
  const float* wk = (const float*)d_in[2];
  const float* wv = (const float*)d_in[3];
  const float* wo = (const float*)d_in[4];
  float* out = (float*)d_out;

  char* ws = (char*)d_ws;
  __bf16* xb   = (__bf16*)(ws);               // 16 MB [8192,1024]; reused as Ab
  __bf16* wqkv = (__bf16*)(ws + (16l << 20)); //  6 MB [3072,1024]
  __bf16* wob  = (__bf16*)(ws + (22l << 20)); //  2 MB
  __bf16* QKV  = (__bf16*)(ws + (24l << 20)); // 48 MB [8192,3072]
  __bf16* VT   = (__bf16*)(ws + (72l << 20)); // 16 MB [4096,2048] -> 88 MB total
  __bf16* Ab   = xb;                          // x dead after QKV gemm

  cvt_f32_bf16<<<4096, 256, 0, stream>>>(x, xb, 8192 * 1024 / 8);
  cvt_w<<<2048, 256, 0, stream>>>(wq, wk, wv, wo, wqkv, wob);

  // fused QKV projection: [8192,3072] = xb @ wqkv^T  (768 blocks, 3 exact rounds)
  gemm_bt8<__bf16><<<768, 512, 0, stream>>>(xb, wqkv, QKV, 8192, 3072, 1024, 24);

  // V -> VT [b,h,d,s]
  vtrans<<<dim3(16, 16, 4), 256, 0, stream>>>(QKV, VT);

  // causal attention (XCD-grouped 1-D grid of 512) -> Ab
  attn4<<<512, 256, 0, stream>>>(QKV, VT, Ab);

  // output projection (fp32 out)  (256 blocks, 1 exact round)
  gemm_bt8<float><<<256, 512, 0, stream>>>(Ab, wob, out, 8192, 1024, 1024, 8);
}